// Round 1
// baseline (19.830 us; speedup 1.0000x reference)
//
#include <hip/hip_runtime.h>
#include <math.h>

#define DGROUPS 64
#define NG      256
#define DIM     512
#define LPAR    8
#define KNEG    32
#define PPAIRS  (DGROUPS - LPAR)   // 56
#define NCHUNKS 8
#define CHUNK   (NG / NCHUNKS)     // 32
#define CEPS    1e-8f
#define INV_T   10.0f              // 1 / TEMP

// ws layout (floats):
//   [0, 64*8*512)           partial sums: partial[d*8 + c][DIM]
//   [262144, 262144+56)     pos[p]
//   [262208, 262208+56)     en[p]
#define WS_POS_OFF 262144
#define WS_EN_OFF  262208

// ---------------- Kernel A: partial sums of embs over NG ----------------
// grid: 512 blocks (d = b>>3, chunk c = b&7), 128 threads, float4 per thread
__global__ void k_sum_partial(const float* __restrict__ embs,
                              float* __restrict__ partial) {
    const int b = blockIdx.x;
    const int d = b >> 3;
    const int c = b & 7;
    const int t = threadIdx.x;           // 0..127, covers 512 dims as float4
    const float4* src = (const float4*)(embs + (size_t)d * NG * DIM);
    float4 acc = make_float4(0.f, 0.f, 0.f, 0.f);
    int idx = (c * CHUNK) * (DIM / 4) + t;
    #pragma unroll 4
    for (int n = 0; n < CHUNK; ++n) {
        float4 v = src[idx];
        acc.x += v.x; acc.y += v.y; acc.z += v.z; acc.w += v.w;
        idx += DIM / 4;
    }
    ((float4*)(partial + (size_t)b * DIM))[t] = acc;
}

// ---------------- Kernel B: pos[p] = cos(sums[p], sums[p+L]) ----------------
// grid: 56 blocks, 128 threads (4 dims each via float4)
__global__ void k_pos(const float* __restrict__ partial,
                      float* __restrict__ pos) {
    const int p = blockIdx.x;
    const int t = threadIdx.x;
    float4 si = make_float4(0.f, 0.f, 0.f, 0.f);
    float4 sj = make_float4(0.f, 0.f, 0.f, 0.f);
    #pragma unroll
    for (int c = 0; c < NCHUNKS; ++c) {
        float4 a = ((const float4*)(partial + (size_t)(p * NCHUNKS + c) * DIM))[t];
        float4 b = ((const float4*)(partial + (size_t)((p + LPAR) * NCHUNKS + c) * DIM))[t];
        si.x += a.x; si.y += a.y; si.z += a.z; si.w += a.w;
        sj.x += b.x; sj.y += b.y; sj.z += b.z; sj.w += b.w;
    }
    float dot = si.x * sj.x + si.y * sj.y + si.z * sj.z + si.w * sj.w;
    float na  = si.x * si.x + si.y * si.y + si.z * si.z + si.w * si.w;
    float nb  = sj.x * sj.x + sj.y * sj.y + sj.z * sj.z + sj.w * sj.w;

    // block reduce: 2 waves of 64
    #pragma unroll
    for (int off = 32; off >= 1; off >>= 1) {
        dot += __shfl_down(dot, off, 64);
        na  += __shfl_down(na,  off, 64);
        nb  += __shfl_down(nb,  off, 64);
    }
    __shared__ float red[3][2];
    const int wave = t >> 6, lane = t & 63;
    if (lane == 0) { red[0][wave] = dot; red[1][wave] = na; red[2][wave] = nb; }
    __syncthreads();
    if (t == 0) {
        dot = red[0][0] + red[0][1];
        na  = red[1][0] + red[1][1];
        nb  = red[2][0] + red[2][1];
        pos[p] = dot / (fmaxf(sqrtf(na), CEPS) * fmaxf(sqrtf(nb), CEPS));
    }
}

// ---------------- Kernel C: en[p] = sum_dim exp(sim_neg[p,dim]/T) ----------------
// grid: 56 blocks, 512 threads (one dim each)
__global__ void k_neg(const float* __restrict__ g1, const float* __restrict__ g2,
                      const int* __restrict__ neg1, const int* __restrict__ neg2,
                      float* __restrict__ en) {
    const int p = blockIdx.x;
    const int t = threadIdx.x;   // dim
    __shared__ int i1[KNEG], i2[KNEG];
    if (t < KNEG)            i1[t] = neg1[p * KNEG + t];
    else if (t < 2 * KNEG)   i2[t - KNEG] = neg2[p * KNEG + (t - KNEG)];
    __syncthreads();

    float sab = 0.f, saa = 0.f, sbb = 0.f;
    #pragma unroll 8
    for (int k = 0; k < KNEG; ++k) {
        float a = g1[(size_t)i1[k] * DIM + t];
        float b = g2[(size_t)i2[k] * DIM + t];
        sab += a * b; saa += a * a; sbb += b * b;
    }
    float sim = sab / (fmaxf(sqrtf(saa), CEPS) * fmaxf(sqrtf(sbb), CEPS));
    float e = expf(sim * INV_T);

    // block reduce: 8 waves of 64
    #pragma unroll
    for (int off = 32; off >= 1; off >>= 1)
        e += __shfl_down(e, off, 64);
    __shared__ float red[8];
    const int wave = t >> 6, lane = t & 63;
    if (lane == 0) red[wave] = e;
    __syncthreads();
    if (t == 0) {
        float s = 0.f;
        #pragma unroll
        for (int w = 0; w < 8; ++w) s += red[w];
        en[p] = s;
    }
}

// ---------------- Kernel D: final scalar ----------------
__global__ void k_final(const float* __restrict__ pos, const float* __restrict__ en,
                        float* __restrict__ out) {
    const int t = threadIdx.x;   // 64 threads
    float l = 0.f;
    if (t < PPAIRS) {
        float pp  = pos[t] * INV_T;
        float num = expf(pp);
        l = logf(num + en[t]) - pp;   // -log(num/den)
    }
    #pragma unroll
    for (int off = 32; off >= 1; off >>= 1)
        l += __shfl_down(l, off, 64);
    if (t == 0) out[0] = 2.0f * l;
}

extern "C" void kernel_launch(void* const* d_in, const int* in_sizes, int n_in,
                              void* d_out, int out_size, void* d_ws, size_t ws_size,
                              hipStream_t stream) {
    const float* embs = (const float*)d_in[0];
    // d_in[1] = g0 (dead on this output path)
    const float* g1   = (const float*)d_in[2];
    const float* g2   = (const float*)d_in[3];
    const int*   neg1 = (const int*)d_in[4];
    const int*   neg2 = (const int*)d_in[5];
    float* ws  = (float*)d_ws;
    float* out = (float*)d_out;

    float* partial = ws;
    float* pos     = ws + WS_POS_OFF;
    float* en      = ws + WS_EN_OFF;

    k_sum_partial<<<DGROUPS * NCHUNKS, 128, 0, stream>>>(embs, partial);
    k_pos<<<PPAIRS, 128, 0, stream>>>(partial, pos);
    k_neg<<<PPAIRS, 512, 0, stream>>>(g1, g2, neg1, neg2, en);
    k_final<<<1, 64, 0, stream>>>(pos, en, out);
}